// Round 1
// baseline (799.463 us; speedup 1.0000x reference)
//
#include <hip/hip_runtime.h>
#include <math.h>

#define NPTS 512
#define CH   128
#define NB   2
#define KVAL 460   // int(512 * (1 - 0.1))

__device__ __forceinline__ float bf2f(unsigned short u) {
    return __uint_as_float(((unsigned int)u) << 16);
}
__device__ __forceinline__ unsigned short f2bf(float f) {
    unsigned int u = __float_as_uint(f);
    u += 0x7fffu + ((u >> 16) & 1u);   // round-to-nearest-even
    return (unsigned short)(u >> 16);
}

// Pack W2 [64][128] fp32 -> ws as u32[c*32 + o2] = {bf16 W2[2*o2][c], bf16 W2[2*o2+1][c]}
__global__ void prep_w2(const float* __restrict__ W2, unsigned int* __restrict__ w2p) {
    int t = blockIdx.x * 256 + threadIdx.x;
    if (t < CH * 32) {
        int c = t >> 5, o2 = t & 31;
        unsigned int lo = f2bf(W2[(2*o2) * CH + c]);
        unsigned int hi = f2bf(W2[(2*o2+1) * CH + c]);
        w2p[t] = lo | (hi << 16);
    }
}

// One block = 32i x 32j tile. 256 threads. LDS total 63,104 B (<= 64 KB).
template <bool USE_WS>
__global__ __launch_bounds__(256, 2)
void mlp_kernel(const float* __restrict__ vp, const float* __restrict__ ep,
                const float* __restrict__ W1,
                const float* __restrict__ g1, const float* __restrict__ be1,
                const float* __restrict__ m1, const float* __restrict__ v1,
                const float* __restrict__ W2, const unsigned int* __restrict__ w2p,
                const float* __restrict__ g2, const float* __restrict__ be2,
                const float* __restrict__ m2, const float* __restrict__ v2,
                const float* __restrict__ W3, const float* __restrict__ b3,
                float* __restrict__ ep_out, float* __restrict__ ns_out)
{
    __shared__ unsigned short sVI[32*130];   //  8320 B, pad 130 breaks bank aliasing
    __shared__ unsigned short sVJ[32*130];   //  8320 B
    __shared__ unsigned int   sW1p[128*64];  // 32768 B, [c][o2] bf16x2
    __shared__ unsigned short sH1[32*132];   //  8448 B, [ii][o] bf16
    __shared__ float          sEp[32*33];    //  4224 B, [ii][jl]
    __shared__ float          sSc1[128];     //   512 B
    __shared__ float          sSh1[128];     //   512 B

    const int t  = threadIdx.x;
    const int b  = blockIdx.z;
    const int i0 = blockIdx.y * 32;
    const int j0 = blockIdx.x * 32;

    // ---- stage vp tiles (bf16) ----
    for (int k = 0; k < 16; ++k) {
        int idx = t + k*256;
        int r = idx >> 7, c = idx & 127;
        sVI[r*130 + c] = f2bf(vp[(size_t)(b*NPTS + i0 + r)*CH + c]);
        sVJ[r*130 + c] = f2bf(vp[(size_t)(b*NPTS + j0 + r)*CH + c]);
    }
    // ---- stage W1 packed: sW1p[c*64+o2] = {W1[2o2][c], W1[2o2+1][c]} ----
    for (int k = 0; k < 32; ++k) {
        int idx = t + k*256;
        int o2 = idx >> 7, c = idx & 127;
        unsigned int lo = f2bf(W1[(2*o2) * CH + c]);
        unsigned int hi = f2bf(W1[(2*o2+1) * CH + c]);
        sW1p[c*64 + o2] = lo | (hi << 16);
    }
    if (t < 128) {
        float s = g1[t] * rsqrtf(v1[t] + 1e-5f);
        sSc1[t] = s;
        sSh1[t] = be1[t] - m1[t]*s;
    }
    __syncthreads();

    // ---- node_similarity (fp32 accumulate over bf16 vp; ~0.3% << 2% budget) ----
    {
        int jj = t & 31;
        int ib = (t >> 5) << 2;
        for (int q = 0; q < 4; ++q) {
            int ii = ib + q;
            const unsigned short* vi = &sVI[ii*130];
            const unsigned short* vj = &sVJ[jj*130];
            float acc = 0.f;
            #pragma unroll 8
            for (int c = 0; c < CH; ++c) {
                float d = bf2f(vi[c]) - bf2f(vj[c]);
                acc = fmaf(d, d, acc);
            }
            ns_out[(size_t)(b*NPTS + i0 + ii)*NPTS + j0 + jj] = -acc;
        }
    }

    // per-thread constants for layers 2/3
    const int og = t & 31;       // layer1: o = og*4+m ; layer2: o = og*2+m
    const int ig = t >> 5;       // ii = ig*4+k
    const int o2a = og*2, o2b = og*2 + 1;
    float sc2a = g2[o2a] * rsqrtf(v2[o2a] + 1e-5f);
    float sh2a = be2[o2a] - m2[o2a]*sc2a;
    float sc2b = g2[o2b] * rsqrtf(v2[o2b] + 1e-5f);
    float sh2b = be2[o2b] - m2[o2b]*sc2b;
    float w3a = W3[o2a], w3b = W3[o2b];
    float b3v = b3[0];

    // ---- per-j-column chunks ----
    for (int jl = 0; jl < 32; ++jl) {
        // ===== layer 1: h1[32 ii][128 o], thread tile 4ii x 4o =====
        float acc[4][4];
        #pragma unroll
        for (int k = 0; k < 4; ++k)
            #pragma unroll
            for (int m = 0; m < 4; ++m) acc[k][m] = 0.f;

        const unsigned short* vjrow = &sVJ[jl*130];
        #pragma unroll 4
        for (int c = 0; c < CH; ++c) {
            float vj = bf2f(vjrow[c]);
            float d2[4];
            #pragma unroll
            for (int k = 0; k < 4; ++k) {
                float d = bf2f(sVI[(ig*4 + k)*130 + c]) - vj;
                d2[k] = d * d;
            }
            uint2 w = *(const uint2*)&sW1p[c*64 + og*2];
            float w0 = __uint_as_float(w.x << 16);
            float w1v = __uint_as_float(w.x & 0xffff0000u);
            float w2v = __uint_as_float(w.y << 16);
            float w3v = __uint_as_float(w.y & 0xffff0000u);
            #pragma unroll
            for (int k = 0; k < 4; ++k) {
                acc[k][0] = fmaf(d2[k], w0,  acc[k][0]);
                acc[k][1] = fmaf(d2[k], w1v, acc[k][1]);
                acc[k][2] = fmaf(d2[k], w2v, acc[k][2]);
                acc[k][3] = fmaf(d2[k], w3v, acc[k][3]);
            }
        }
        #pragma unroll
        for (int k = 0; k < 4; ++k) {
            int ii = ig*4 + k;
            #pragma unroll
            for (int m = 0; m < 4; ++m) {
                int o = og*4 + m;
                float h = fmaf(acc[k][m], sSc1[o], sSh1[o]);
                h = (h > 0.f) ? h : h * 0.01f;
                sH1[ii*132 + o] = f2bf(h);
            }
        }
        __syncthreads();

        // ===== layer 2: h2[32 ii][64 o], thread tile 4ii x 2o, h2 stays in regs =====
        float acc2[4][2];
        #pragma unroll
        for (int k = 0; k < 4; ++k) { acc2[k][0] = 0.f; acc2[k][1] = 0.f; }

        #pragma unroll 4
        for (int c = 0; c < CH; ++c) {
            unsigned int w;
            if (USE_WS) {
                w = w2p[c*32 + og];                       // L1-resident packed bf16x2
            } else {
                unsigned int lo = f2bf(W2[(2*og) * CH + c]);
                unsigned int hi = f2bf(W2[(2*og+1) * CH + c]);
                w = lo | (hi << 16);
            }
            float w0 = __uint_as_float(w << 16);
            float w1v = __uint_as_float(w & 0xffff0000u);
            #pragma unroll
            for (int k = 0; k < 4; ++k) {
                float h = bf2f(sH1[(ig*4 + k)*132 + c]);
                acc2[k][0] = fmaf(h, w0,  acc2[k][0]);
                acc2[k][1] = fmaf(h, w1v, acc2[k][1]);
            }
        }

        // ===== layer 3: BN2 + lrelu + dot with W3, reduce across og lanes =====
        float part[4];
        #pragma unroll
        for (int k = 0; k < 4; ++k) {
            float ha = fmaf(acc2[k][0], sc2a, sh2a); ha = (ha > 0.f) ? ha : ha*0.01f;
            float hb = fmaf(acc2[k][1], sc2b, sh2b); hb = (hb > 0.f) ? hb : hb*0.01f;
            part[k] = fmaf(ha, w3a, hb * w3b);
        }
        #pragma unroll
        for (int k = 0; k < 4; ++k) {
            part[k] += __shfl_xor(part[k], 16);
            part[k] += __shfl_xor(part[k], 8);
            part[k] += __shfl_xor(part[k], 4);
            part[k] += __shfl_xor(part[k], 2);
            part[k] += __shfl_xor(part[k], 1);
        }
        if (og == 0) {
            #pragma unroll
            for (int k = 0; k < 4; ++k) {
                int ii = ig*4 + k;
                int i = i0 + ii, j = j0 + jl;
                float logit = part[k] + b3v;
                float sg = 1.f / (1.f + __expf(-logit));
                float epl = (i == j) ? 0.f : ep[(size_t)(b*NPTS + i)*NPTS + j];
                sEp[ii*33 + jl] = sg * epl;
            }
        }
        __syncthreads();   // protects sH1 (next chunk) and sEp
    }

    // ---- coalesced tile writeout ----
    for (int k = 0; k < 4; ++k) {
        int idx = t + k*256;
        int ii = idx >> 5, jj = idx & 31;
        ep_out[(size_t)(b*NPTS + i0 + ii)*NPTS + j0 + jj] = sEp[ii*33 + jj];
    }
}

// ---- kernel 2: per-row top-k mask + L1 renorm + diag + row norm, in place ----
__device__ __forceinline__ float block_reduce_sum(float v, float* red) {
    #pragma unroll
    for (int off = 32; off; off >>= 1) v += __shfl_down(v, off);
    int wid = threadIdx.x >> 6;
    if ((threadIdx.x & 63) == 0) red[wid] = v;
    __syncthreads();
    float s = red[0] + red[1] + red[2] + red[3];
    __syncthreads();
    return s;
}

__global__ __launch_bounds__(256)
void topk_norm_kernel(const float* __restrict__ ep_gen, float* __restrict__ ep_io) {
    __shared__ float r[512];
    __shared__ float red[4];
    const int row = blockIdx.x;          // b*512 + i
    const int i   = row & (NPTS - 1);
    const int t   = threadIdx.x;
    const float* gen = &ep_gen[(size_t)row * NPTS];
    float* io        = &ep_io [(size_t)row * NPTS];

    float v0 = io[t], v1 = io[t + 256];
    r[t] = v0; r[t + 256] = v1;
    float g0 = (t       == i) ? 0.f : gen[t];
    float g1 = (t + 256 == i) ? 0.f : gen[t + 256];
    __syncthreads();

    float s_last = block_reduce_sum(g0 + g1, red);

    // exact stable rank (matches lax.top_k tie order: lower index wins)
    int c0 = 0, c1 = 0;
    #pragma unroll 8
    for (int k = 0; k < NPTS; ++k) {
        float rv = r[k];
        c0 += (rv > v0) || (rv == v0 && k < t);
        c1 += (rv > v1) || (rv == v1 && k < (t + 256));
    }
    float m0 = (c0 < KVAL) ? v0 : 0.f;
    float m1 = (c1 < KVAL) ? v1 : 0.f;

    float l1 = block_reduce_sum(m0 + m1, red);
    l1 = fmaxf(l1, 1e-12f);
    float scale = s_last / l1;
    float f0 = m0*scale + ((t       == i) ? 1.f : 0.f) + 1e-6f;
    float f1 = m1*scale + ((t + 256 == i) ? 1.f : 0.f) + 1e-6f;

    float s2 = block_reduce_sum(f0 + f1, red);
    float inv = 1.f / s2;
    io[t]       = f0 * inv;
    io[t + 256] = f1 * inv;
}

extern "C" void kernel_launch(void* const* d_in, const int* in_sizes, int n_in,
                              void* d_out, int out_size, void* d_ws, size_t ws_size,
                              hipStream_t stream) {
    const float* vp  = (const float*)d_in[0];
    const float* ep  = (const float*)d_in[1];
    const float* W1  = (const float*)d_in[2];
    const float* g1  = (const float*)d_in[3];
    const float* be1 = (const float*)d_in[4];
    const float* m1  = (const float*)d_in[5];
    const float* v1  = (const float*)d_in[6];
    const float* W2  = (const float*)d_in[7];
    const float* g2  = (const float*)d_in[8];
    const float* be2 = (const float*)d_in[9];
    const float* m2  = (const float*)d_in[10];
    const float* v2  = (const float*)d_in[11];
    const float* W3  = (const float*)d_in[12];
    const float* b3  = (const float*)d_in[13];

    float* out    = (float*)d_out;
    float* ep_out = out;                          // [2,512,512]
    float* ns_out = out + (size_t)NB*NPTS*NPTS;   // [2,512,512]

    dim3 grid(NPTS/32, NPTS/32, NB);
    dim3 blk(256);

    if (ws_size >= (size_t)(CH * 32 * 4)) {
        unsigned int* w2p = (unsigned int*)d_ws;
        prep_w2<<<dim3(16), blk, 0, stream>>>(W2, w2p);
        mlp_kernel<true><<<grid, blk, 0, stream>>>(vp, ep, W1, g1, be1, m1, v1,
                                                   W2, w2p, g2, be2, m2, v2, W3, b3,
                                                   ep_out, ns_out);
    } else {
        mlp_kernel<false><<<grid, blk, 0, stream>>>(vp, ep, W1, g1, be1, m1, v1,
                                                    W2, nullptr, g2, be2, m2, v2, W3, b3,
                                                    ep_out, ns_out);
    }
    topk_norm_kernel<<<dim3(NB*NPTS), blk, 0, stream>>>(ep, ep_out);
}

// Round 2
// 193.106 us; speedup vs baseline: 4.1400x; 4.1400x over previous
//
#include <hip/hip_runtime.h>
#include <math.h>

#define NPTS 512
#define CH   128
#define NB   2
#define KVAL 460   // int(512 * (1 - 0.1))

typedef __attribute__((ext_vector_type(8))) short short8;
typedef __attribute__((ext_vector_type(4))) float f32x4;

union S8U { short8 s8; unsigned u[4]; };

__device__ __forceinline__ unsigned short f2bf_rne(float f) {
    unsigned int u = __float_as_uint(f);
    u += 0x7fffu + ((u >> 16) & 1u);   // round-to-nearest-even
    return (unsigned short)(u >> 16);
}
// pack two f32 -> {bf16(a) lo, bf16(b) hi} by truncation: one v_perm_b32
__device__ __forceinline__ unsigned pk_trunc(float a, float b) {
    return __builtin_amdgcn_perm(__float_as_uint(b), __float_as_uint(a), 0x07060302u);
}

// One block = 32i x 32j tile (1024 pairs), 4 waves.
// Wave w: h = w&1 -> row half (32 of 64 chunk rows), g = w>>1 -> channel half.
// W1 (bf16 B-frags, 64 VGPR) and W2 (32 VGPR) cached in registers per wave.
__global__ __launch_bounds__(256, 2)
void mlp_mfma_kernel(const float* __restrict__ vp, const float* __restrict__ ep,
                     const float* __restrict__ W1,
                     const float* __restrict__ g1, const float* __restrict__ be1,
                     const float* __restrict__ m1, const float* __restrict__ v1,
                     const float* __restrict__ W2,
                     const float* __restrict__ g2, const float* __restrict__ be2,
                     const float* __restrict__ m2, const float* __restrict__ v2,
                     const float* __restrict__ W3, const float* __restrict__ b3,
                     float* __restrict__ ep_out, float* __restrict__ ns_out)
{
    __shared__ __align__(16) float sVI[32*132];          // 16,896 B (stride 132: bank shift 4)
    __shared__ __align__(16) float sVJ[32*132];          // 16,896 B
    __shared__ __align__(16) unsigned short sH1[64*136]; // 17,408 B (stride 136: 16B-aligned, shift 4)
    __shared__ float sPart[2][64];                       //    512 B

    const int t    = threadIdx.x;
    const int lane = t & 63;
    const int w    = t >> 6;
    const int h    = w & 1;
    const int g    = w >> 1;
    const int l15  = lane & 15;
    const int q    = lane >> 4;
    const int q8   = q * 8;
    const int b    = blockIdx.z;
    const int i0   = blockIdx.y * 32;
    const int j0   = blockIdx.x * 32;

    // ---- stage vp tiles in fp32 (coalesced float4) ----
    for (int k = 0; k < 4; ++k) {
        int idx = k*256 + t;
        int r = idx >> 5, c4 = (idx & 31) * 4;
        *(float4*)&sVI[r*132 + c4] = *(const float4*)&vp[((size_t)(b*NPTS + i0 + r))*CH + c4];
        *(float4*)&sVJ[r*132 + c4] = *(const float4*)&vp[((size_t)(b*NPTS + j0 + r))*CH + c4];
    }

    // ---- W1/W2 bf16 B-fragments into registers (one-time, from L2) ----
    short8 w1f[4][4];
    #pragma unroll
    for (int nt = 0; nt < 4; ++nt) {
        int o = g*64 + nt*16 + l15;
        #pragma unroll
        for (int kt = 0; kt < 4; ++kt) {
            const float* p = &W1[(size_t)o*CH + kt*32 + q8];
            float4 x0 = *(const float4*)p;
            float4 x1 = *(const float4*)(p + 4);
            S8U u;
            u.u[0] = (unsigned)f2bf_rne(x0.x) | ((unsigned)f2bf_rne(x0.y) << 16);
            u.u[1] = (unsigned)f2bf_rne(x0.z) | ((unsigned)f2bf_rne(x0.w) << 16);
            u.u[2] = (unsigned)f2bf_rne(x1.x) | ((unsigned)f2bf_rne(x1.y) << 16);
            u.u[3] = (unsigned)f2bf_rne(x1.z) | ((unsigned)f2bf_rne(x1.w) << 16);
            w1f[nt][kt] = u.s8;
        }
    }
    short8 w2f[2][4];
    #pragma unroll
    for (int nt = 0; nt < 2; ++nt) {
        int o = g*32 + nt*16 + l15;
        #pragma unroll
        for (int kt = 0; kt < 4; ++kt) {
            const float* p = &W2[(size_t)o*CH + kt*32 + q8];
            float4 x0 = *(const float4*)p;
            float4 x1 = *(const float4*)(p + 4);
            S8U u;
            u.u[0] = (unsigned)f2bf_rne(x0.x) | ((unsigned)f2bf_rne(x0.y) << 16);
            u.u[1] = (unsigned)f2bf_rne(x0.z) | ((unsigned)f2bf_rne(x0.w) << 16);
            u.u[2] = (unsigned)f2bf_rne(x1.x) | ((unsigned)f2bf_rne(x1.y) << 16);
            u.u[3] = (unsigned)f2bf_rne(x1.z) | ((unsigned)f2bf_rne(x1.w) << 16);
            w2f[nt][kt] = u.s8;
        }
    }

    // ---- BN constants (per-lane, registers) ----
    float sc1v[4], sh1v[4];
    #pragma unroll
    for (int nt = 0; nt < 4; ++nt) {
        int o = g*64 + nt*16 + l15;
        float s = g1[o] * rsqrtf(v1[o] + 1e-5f);
        sc1v[nt] = s;
        sh1v[nt] = be1[o] - m1[o]*s;
    }
    float sc2v[2], sh2v[2], w3v[2];
    #pragma unroll
    for (int nt = 0; nt < 2; ++nt) {
        int o = g*32 + nt*16 + l15;
        float s = g2[o] * rsqrtf(v2[o] + 1e-5f);
        sc2v[nt] = s;
        sh2v[nt] = be2[o] - m2[o]*s;
        w3v[nt]  = W3[o];
    }
    const float b3v = b3[0];
    __syncthreads();

    // ---- 16 chunks of 64 pair-rows: m_local = h*32 + ms*16 + (l&15); ii=ch*2+h, jl=ms*16+(l&15)
    #pragma unroll 1
    for (int ch = 0; ch < 16; ++ch) {
        const int iirow = ch*2 + h;

        // ===== layer 1: A-frags built directly in MFMA layout; ns for free (fp32) =====
        #pragma unroll
        for (int ms = 0; ms < 2; ++ms) {
            const int rowbase = h*32 + ms*16;
            short8 afr[4];
            float ns = 0.f;
            #pragma unroll
            for (int kt = 0; kt < 4; ++kt) {
                const float* vi = &sVI[iirow*132 + kt*32 + q8];           // wave-uniform row (broadcast)
                const float* vj = &sVJ[(ms*16 + l15)*132 + kt*32 + q8];   // per-lane row
                float4 a0 = *(const float4*)vi, a1 = *(const float4*)(vi + 4);
                float4 c0 = *(const float4*)vj, c1 = *(const float4*)(vj + 4);
                float d0 = a0.x - c0.x, d1 = a0.y - c0.y, d2 = a0.z - c0.z, d3 = a0.w - c0.w;
                float d4 = a1.x - c1.x, d5 = a1.y - c1.y, d6 = a1.z - c1.z, d7 = a1.w - c1.w;
                float p0 = d0*d0, p1 = d1*d1, p2 = d2*d2, p3 = d3*d3;
                float p4 = d4*d4, p5 = d5*d5, p6 = d6*d6, p7 = d7*d7;
                ns += ((p0 + p1) + (p2 + p3)) + ((p4 + p5) + (p6 + p7));
                S8U u;
                u.u[0] = pk_trunc(p0, p1);
                u.u[1] = pk_trunc(p2, p3);
                u.u[2] = pk_trunc(p4, p5);
                u.u[3] = pk_trunc(p6, p7);
                afr[kt] = u.s8;
            }
            // node_similarity: reduce over k-quads (lanes same l15 differ in q)
            ns += __shfl_xor(ns, 16);
            ns += __shfl_xor(ns, 32);
            if (g == 0 && lane < 16) {
                int i = i0 + iirow, j = j0 + ms*16 + lane;
                ns_out[((size_t)(b*NPTS + i))*NPTS + j] = -ns;
            }
            #pragma unroll
            for (int nt = 0; nt < 4; ++nt) {
                f32x4 acc = {0.f, 0.f, 0.f, 0.f};
                acc = __builtin_amdgcn_mfma_f32_16x16x32_bf16(afr[0], w1f[nt][0], acc, 0, 0, 0);
                acc = __builtin_amdgcn_mfma_f32_16x16x32_bf16(afr[1], w1f[nt][1], acc, 0, 0, 0);
                acc = __builtin_amdgcn_mfma_f32_16x16x32_bf16(afr[2], w1f[nt][2], acc, 0, 0, 0);
                acc = __builtin_amdgcn_mfma_f32_16x16x32_bf16(afr[3], w1f[nt][3], acc, 0, 0, 0);
                const int obase = g*64 + nt*16 + l15;
                #pragma unroll
                for (int r = 0; r < 4; ++r) {
                    float hv = fmaf(acc[r], sc1v[nt], sh1v[nt]);
                    hv = hv > 0.f ? hv : hv * 0.01f;
                    sH1[(rowbase + q*4 + r)*136 + obase] = (unsigned short)(__float_as_uint(hv) >> 16);
                }
            }
        }
        __syncthreads();

        // ===== layers 2+3 =====
        #pragma unroll
        for (int ms = 0; ms < 2; ++ms) {
            const int rowbase = h*32 + ms*16;
            short8 hfr[4];
            #pragma unroll
            for (int kt = 0; kt < 4; ++kt)
                hfr[kt] = *(const short8*)&sH1[(rowbase + l15)*136 + kt*32 + q8];
            float part[4] = {0.f, 0.f, 0.f, 0.f};
            #pragma unroll
            for (int nt = 0; nt < 2; ++nt) {
                f32x4 acc = {0.f, 0.f, 0.f, 0.f};
                acc = __builtin_amdgcn_mfma_f32_16x16x32_bf16(hfr[0], w2f[nt][0], acc, 0, 0, 0);
                acc = __builtin_amdgcn_mfma_f32_16x16x32_bf16(hfr[1], w2f[nt][1], acc, 0, 0, 0);
                acc = __builtin_amdgcn_mfma_f32_16x16x32_bf16(hfr[2], w2f[nt][2], acc, 0, 0, 0);
                acc = __builtin_amdgcn_mfma_f32_16x16x32_bf16(hfr[3], w2f[nt][3], acc, 0, 0, 0);
                #pragma unroll
                for (int r = 0; r < 4; ++r) {
                    float hv = fmaf(acc[r], sc2v[nt], sh2v[nt]);
                    hv = hv > 0.f ? hv : hv * 0.01f;
                    part[r] = fmaf(hv, w3v[nt], part[r]);
                }
            }
            #pragma unroll
            for (int r = 0; r < 4; ++r) {
                part[r] += __shfl_xor(part[r], 1);
                part[r] += __shfl_xor(part[r], 2);
                part[r] += __shfl_xor(part[r], 4);
                part[r] += __shfl_xor(part[r], 8);
            }
            if (l15 == 0) {
                #pragma unroll
                for (int r = 0; r < 4; ++r)
                    sPart[g][rowbase + q*4 + r] = part[r];
            }
        }
        __syncthreads();

        // ===== epilogue: logits -> sigmoid * ep_last, direct global write =====
        if (t < 64) {
            float logit = sPart[0][t] + sPart[1][t] + b3v;
            float sg = 1.f / (1.f + __expf(-logit));
            int i = i0 + ch*2 + (t >> 5);
            int j = j0 + (t & 31);
            float epl = (i == j) ? 0.f : ep[((size_t)(b*NPTS + i))*NPTS + j];
            ep_out[((size_t)(b*NPTS + i))*NPTS + j] = sg * epl;
        }
        // next chunk's sH1 writes are safe: all sH1 reads completed before the
        // second barrier; sPart is only rewritten after the next first barrier.
    }
}

// ---- kernel 2: per-row top-k mask + L1 renorm + diag + row norm, in place ----
__device__ __forceinline__ float block_reduce_sum(float v, float* red) {
    #pragma unroll
    for (int off = 32; off; off >>= 1) v += __shfl_down(v, off);
    int wid = threadIdx.x >> 6;
    if ((threadIdx.x & 63) == 0) red[wid] = v;
    __syncthreads();
    float s = red[0] + red[1] + red[2] + red[3];
    __syncthreads();
    return s;
}

__global__ __launch_bounds__(256)
void topk_norm_kernel(const float* __restrict__ ep_gen, float* __restrict__ ep_io) {
    __shared__ float r[512];
    __shared__ float red[4];
    const int row = blockIdx.x;          // b*512 + i
    const int i   = row & (NPTS - 1);
    const int t   = threadIdx.x;
    const float* gen = &ep_gen[(size_t)row * NPTS];
    float* io        = &ep_io [(size_t)row * NPTS];

    float v0 = io[t], v1 = io[t + 256];
    r[t] = v0; r[t + 256] = v1;
    float g0 = (t       == i) ? 0.f : gen[t];
    float g1 = (t + 256 == i) ? 0.f : gen[t + 256];
    __syncthreads();

    float s_last = block_reduce_sum(g0 + g1, red);

    // exact stable rank (matches lax.top_k tie order: lower index wins)
    int c0 = 0, c1 = 0;
    #pragma unroll 8
    for (int k = 0; k < NPTS; ++k) {
        float rv = r[k];
        c0 += (rv > v0) || (rv == v0 && k < t);
        c1 += (rv > v1) || (rv == v1 && k < (t + 256));
    }
    float m0 = (c0 < KVAL) ? v0 : 0.f;
    float m1 = (c1 < KVAL) ? v1 : 0.f;

    float l1 = block_reduce_sum(m0 + m1, red);
    l1 = fmaxf(l1, 1e-12f);
    float scale = s_last / l1;
    float f0 = m0*scale + ((t       == i) ? 1.f : 0.f) + 1e-6f;
    float f1 = m1*scale + ((t + 256 == i) ? 1.f : 0.f) + 1e-6f;

    float s2 = block_reduce_sum(f0 + f1, red);
    float inv = 1.f / s2;
    io[t]       = f0 * inv;
    io[t + 256] = f1 * inv;
}

extern "C" void kernel_launch(void* const* d_in, const int* in_sizes, int n_in,
                              void* d_out, int out_size, void* d_ws, size_t ws_size,
                              hipStream_t stream) {
    const float* vp  = (const float*)d_in[0];
    const float* ep  = (const float*)d_in[1];
    const float* W1  = (const float*)d_in[2];
    const float* g1  = (const float*)d_in[3];
    const float* be1 = (const float*)d_in[4];
    const float* m1  = (const float*)d_in[5];
    const float* v1  = (const float*)d_in[6];
    const float* W2  = (const float*)d_in[7];
    const float* g2  = (const float*)d_in[8];
    const float* be2 = (const float*)d_in[9];
    const float* m2  = (const float*)d_in[10];
    const float* v2  = (const float*)d_in[11];
    const float* W3  = (const float*)d_in[12];
    const float* b3  = (const float*)d_in[13];

    float* out    = (float*)d_out;
    float* ep_out = out;                          // [2,512,512]
    float* ns_out = out + (size_t)NB*NPTS*NPTS;   // [2,512,512]

    dim3 grid(NPTS/32, NPTS/32, NB);
    mlp_mfma_kernel<<<grid, dim3(256), 0, stream>>>(vp, ep, W1, g1, be1, m1, v1,
                                                    W2, g2, be2, m2, v2, W3, b3,
                                                    ep_out, ns_out);
    topk_norm_kernel<<<dim3(NB*NPTS), dim3(256), 0, stream>>>(ep, ep_out);
}